// Round 1
// baseline (861.380 us; speedup 1.0000x reference)
//
#include <hip/hip_runtime.h>

#define F_IN 256
#define F_OUT 128
#define ALPHA 0.2f

// ---------------- asum: column sums of a [256,256] -> asum[256] ----------------
__global__ __launch_bounds__(256) void asum_kernel(const float* __restrict__ a,
                                                   float* __restrict__ asum) {
    int j = threadIdx.x;  // 0..255
    float s = 0.f;
    #pragma unroll 8
    for (int i = 0; i < 2 * F_OUT; ++i) s += a[i * (2 * F_OUT) + j];
    asum[j] = s;
}

// ---------------- GEMM: h[n,128] = x[n,256] @ W[256,128], fp32 ----------------
// Block: 256 threads, computes 32 rows x 128 cols. Thread: 4x4 register tile.
#define GR 32
#define GK 64
__global__ __launch_bounds__(256) void gemm_kernel(const float* __restrict__ x,
                                                   const float* __restrict__ W,
                                                   float* __restrict__ h, int n) {
    __shared__ float xs[GR][GK];       // 8 KB
    __shared__ float wsm[GK][F_OUT];   // 32 KB
    const int t = threadIdx.x;
    const int row0 = blockIdx.x * GR;
    const int tx = t & 31;   // col group: cols tx*4 .. tx*4+3
    const int ty = t >> 5;   // row group: rows ty*4 .. ty*4+3

    float acc[4][4] = {{0.f}};

    for (int kt = 0; kt < F_IN; kt += GK) {
        // load x tile (32 x 64): 512 float4, 2 per thread; clamp OOB rows
        #pragma unroll
        for (int it = 0; it < 2; ++it) {
            int i = t + it * 256;
            int r = i >> 4;          // /16 float4 per row
            int c = i & 15;
            int row = row0 + r;
            if (row >= n) row = n - 1;
            float4 v = *(const float4*)(&x[(size_t)row * F_IN + kt + c * 4]);
            *(float4*)(&xs[r][c * 4]) = v;
        }
        // load W tile (64 x 128): contiguous 8192 floats = 2048 float4, 8 per thread
        const float4* Wg = (const float4*)(W + (size_t)kt * F_OUT);
        float4* Wl = (float4*)(&wsm[0][0]);
        #pragma unroll
        for (int it = 0; it < 8; ++it) Wl[t + it * 256] = Wg[t + it * 256];
        __syncthreads();

        #pragma unroll 8
        for (int k = 0; k < GK; ++k) {
            float4 wv = *(float4*)(&wsm[k][tx * 4]);
            float xr[4];
            #pragma unroll
            for (int r = 0; r < 4; ++r) xr[r] = xs[ty * 4 + r][k];
            #pragma unroll
            for (int r = 0; r < 4; ++r) {
                acc[r][0] += xr[r] * wv.x;
                acc[r][1] += xr[r] * wv.y;
                acc[r][2] += xr[r] * wv.z;
                acc[r][3] += xr[r] * wv.w;
            }
        }
        __syncthreads();
    }

    #pragma unroll
    for (int r = 0; r < 4; ++r) {
        int row = row0 + ty * 4 + r;
        if (row < n) {
            float4 v = make_float4(acc[r][0], acc[r][1], acc[r][2], acc[r][3]);
            *(float4*)(&h[(size_t)row * F_OUT + tx * 4]) = v;
        }
    }
}

// ---------------- edge kernel: one wave per edge ----------------
// lane l owns features (2l, 2l+1). Computes lin, conv via butterfly reduce,
// then edge_e and atomic accumulation into hp (d_out) and rowsum.
__global__ __launch_bounds__(256) void edge_kernel(const float* __restrict__ h,
                                                   const int* __restrict__ src,
                                                   const int* __restrict__ dst,
                                                   const float* __restrict__ asum,
                                                   float* __restrict__ hp,
                                                   float* __restrict__ rowsum,
                                                   int E) {
    const int lane = threadIdx.x & 63;
    const float2 a1 = ((const float2*)asum)[lane];            // asum[0..127]
    const float2 a2 = ((const float2*)(asum + F_OUT))[lane];  // asum[128..255]
    const int wave = (blockIdx.x * blockDim.x + threadIdx.x) >> 6;
    const int nwaves = (gridDim.x * blockDim.x) >> 6;

    for (int e = wave; e < E; e += nwaves) {
        const int s = src[e];
        const int d = dst[e];
        const float2 hs = ((const float2*)(h + (size_t)s * F_OUT))[lane];
        const float2 hd = ((const float2*)(h + (size_t)d * F_OUT))[lane];

        float plin = hs.x * a1.x + hs.y * a1.y + hd.x * a2.x + hd.y * a2.y;
        float pconv = hs.x * hd.x + hs.y * hd.y;
        #pragma unroll
        for (int m = 32; m >= 1; m >>= 1) {
            plin += __shfl_xor(plin, m, 64);
            pconv += __shfl_xor(pconv, m, 64);
        }
        const float sig = 1.0f / (1.0f + __expf(-pconv));
        const float z = plin * sig;
        const float lr = (z >= 0.f) ? z : ALPHA * z;
        const float ee = __expf(-lr);

        atomicAdd(&hp[(size_t)s * F_OUT + 2 * lane], ee * hd.x);
        atomicAdd(&hp[(size_t)s * F_OUT + 2 * lane + 1], ee * hd.y);
        if (lane == 0) atomicAdd(&rowsum[s], ee);
    }
}

// ---------------- finalize: out = elu(hp / (rowsum + 1e-8)) ----------------
__global__ __launch_bounds__(256) void final_kernel(float* __restrict__ out,
                                                    const float* __restrict__ rowsum,
                                                    int n) {
    const int i = blockIdx.x * blockDim.x + threadIdx.x;  // float4 index
    const int total = n * (F_OUT / 4);
    if (i >= total) return;
    const int row = i >> 5;  // 32 float4 per row
    const float inv = 1.0f / (rowsum[row] + 1e-8f);
    float4 v = ((float4*)out)[i];
    v.x *= inv; v.y *= inv; v.z *= inv; v.w *= inv;
    v.x = (v.x > 0.f) ? v.x : (__expf(v.x) - 1.f);
    v.y = (v.y > 0.f) ? v.y : (__expf(v.y) - 1.f);
    v.z = (v.z > 0.f) ? v.z : (__expf(v.z) - 1.f);
    v.w = (v.w > 0.f) ? v.w : (__expf(v.w) - 1.f);
    ((float4*)out)[i] = v;
}

extern "C" void kernel_launch(void* const* d_in, const int* in_sizes, int n_in,
                              void* d_out, int out_size, void* d_ws, size_t ws_size,
                              hipStream_t stream) {
    const float* x = (const float*)d_in[0];
    const int* ei = (const int*)d_in[1];
    const float* W = (const float*)d_in[2];
    const float* a = (const float*)d_in[3];
    float* out = (float*)d_out;

    const int n = in_sizes[0] / F_IN;
    const int E = in_sizes[1] / 2;
    const int* src = ei;
    const int* dst = ei + E;

    char* wsb = (char*)d_ws;
    float* h = (float*)wsb;                                    // n*128 floats
    float* rowsum = (float*)(wsb + (size_t)n * F_OUT * 4);     // n floats
    float* asum = rowsum + n;                                  // 256 floats

    // zero accumulators (ws/out are poisoned before every timed launch)
    hipMemsetAsync(d_out, 0, (size_t)out_size * sizeof(float), stream);
    hipMemsetAsync(rowsum, 0, (size_t)n * sizeof(float), stream);

    asum_kernel<<<1, 256, 0, stream>>>(a, asum);
    gemm_kernel<<<(n + GR - 1) / GR, 256, 0, stream>>>(x, W, h, n);
    edge_kernel<<<2048, 256, 0, stream>>>(h, src, dst, asum, out, rowsum, E);
    final_kernel<<<(n * (F_OUT / 4) + 255) / 256, 256, 0, stream>>>(out, rowsum, n);
}

// Round 2
// 356.205 us; speedup vs baseline: 2.4182x; 2.4182x over previous
//
#include <hip/hip_runtime.h>

#define F_IN 256
#define F_OUT 128
#define ALPHA 0.2f

// ---------------- asum: column sums of a [256,256] -> asum[256] ----------------
__global__ __launch_bounds__(256) void asum_kernel(const float* __restrict__ a,
                                                   float* __restrict__ asum) {
    int j = threadIdx.x;  // 0..255
    float s = 0.f;
    #pragma unroll 8
    for (int i = 0; i < 2 * F_OUT; ++i) s += a[i * (2 * F_OUT) + j];
    asum[j] = s;
}

// ---------------- GEMM: h[n,128] = x[n,256] @ W[256,128], fp32 ----------------
#define GR 32
#define GK 64
__global__ __launch_bounds__(256) void gemm_kernel(const float* __restrict__ x,
                                                   const float* __restrict__ W,
                                                   float* __restrict__ h, int n) {
    __shared__ float xs[GR][GK];       // 8 KB
    __shared__ float wsm[GK][F_OUT];   // 32 KB
    const int t = threadIdx.x;
    const int row0 = blockIdx.x * GR;
    const int tx = t & 31;
    const int ty = t >> 5;

    float acc[4][4] = {{0.f}};

    for (int kt = 0; kt < F_IN; kt += GK) {
        #pragma unroll
        for (int it = 0; it < 2; ++it) {
            int i = t + it * 256;
            int r = i >> 4;
            int c = i & 15;
            int row = row0 + r;
            if (row >= n) row = n - 1;
            float4 v = *(const float4*)(&x[(size_t)row * F_IN + kt + c * 4]);
            *(float4*)(&xs[r][c * 4]) = v;
        }
        const float4* Wg = (const float4*)(W + (size_t)kt * F_OUT);
        float4* Wl = (float4*)(&wsm[0][0]);
        #pragma unroll
        for (int it = 0; it < 8; ++it) Wl[t + it * 256] = Wg[t + it * 256];
        __syncthreads();

        #pragma unroll 8
        for (int k = 0; k < GK; ++k) {
            float4 wv = *(float4*)(&wsm[k][tx * 4]);
            float xr[4];
            #pragma unroll
            for (int r = 0; r < 4; ++r) xr[r] = xs[ty * 4 + r][k];
            #pragma unroll
            for (int r = 0; r < 4; ++r) {
                acc[r][0] += xr[r] * wv.x;
                acc[r][1] += xr[r] * wv.y;
                acc[r][2] += xr[r] * wv.z;
                acc[r][3] += xr[r] * wv.w;
            }
        }
        __syncthreads();
    }

    #pragma unroll
    for (int r = 0; r < 4; ++r) {
        int row = row0 + ty * 4 + r;
        if (row < n) {
            float4 v = make_float4(acc[r][0], acc[r][1], acc[r][2], acc[r][3]);
            *(float4*)(&h[(size_t)row * F_OUT + tx * 4]) = v;
        }
    }
}

// ---------------- CSR build ----------------
__global__ __launch_bounds__(256) void hist_kernel(const int* __restrict__ src,
                                                   int* __restrict__ cnt, int E) {
    int i = blockIdx.x * blockDim.x + threadIdx.x;
    if (i < E) atomicAdd(&cnt[src[i]], 1);
}

// Block-local exclusive scan; emits per-block exclusive prefixes + block sums.
__global__ __launch_bounds__(256) void scan1_kernel(const int* __restrict__ cnt,
                                                    int* __restrict__ partial,
                                                    int* __restrict__ bsums, int n) {
    const int i = blockIdx.x * 256 + threadIdx.x;
    const int lane = threadIdx.x & 63;
    const int wid = threadIdx.x >> 6;
    int v = (i < n) ? cnt[i] : 0;
    int x = v;
    #pragma unroll
    for (int m = 1; m < 64; m <<= 1) {
        int y = __shfl_up(x, m, 64);
        if (lane >= m) x += y;
    }
    __shared__ int wsum[4];
    if (lane == 63) wsum[wid] = x;
    __syncthreads();
    int ws0 = 0;
    for (int w = 0; w < wid; ++w) ws0 += wsum[w];
    int incl = x + ws0;
    if (i < n) partial[i] = incl - v;            // block-local exclusive
    if (threadIdx.x == 255) bsums[blockIdx.x] = incl;  // block total
}

// Exclusive scan of block sums (nb <= 256), single block.
__global__ __launch_bounds__(256) void scan2_kernel(int* __restrict__ bsums, int nb) {
    const int t = threadIdx.x;
    const int lane = t & 63;
    const int wid = t >> 6;
    int v = (t < nb) ? bsums[t] : 0;
    int x = v;
    #pragma unroll
    for (int m = 1; m < 64; m <<= 1) {
        int y = __shfl_up(x, m, 64);
        if (lane >= m) x += y;
    }
    __shared__ int wsum[4];
    if (lane == 63) wsum[wid] = x;
    __syncthreads();
    int ws0 = 0;
    for (int w = 0; w < wid; ++w) ws0 += wsum[w];
    if (t < nb) bsums[t] = x + ws0 - v;          // exclusive
}

__global__ __launch_bounds__(256) void scatter_kernel(const int* __restrict__ src,
                                                      const int* __restrict__ dst,
                                                      const int* __restrict__ partial,
                                                      const int* __restrict__ bscan,
                                                      int* __restrict__ cur,
                                                      int* __restrict__ sdst, int E) {
    int i = blockIdx.x * blockDim.x + threadIdx.x;
    if (i >= E) return;
    int s = src[i];
    int pos = partial[s] + bscan[s >> 8] + atomicAdd(&cur[s], 1);
    sdst[pos] = dst[i];
}

// ---------------- aggregation: one wave per node, no atomics ----------------
__global__ __launch_bounds__(256) void agg_kernel(const float* __restrict__ h,
                                                  const int* __restrict__ sdst,
                                                  const int* __restrict__ partial,
                                                  const int* __restrict__ bscan,
                                                  const int* __restrict__ cnt,
                                                  const float* __restrict__ asum,
                                                  float* __restrict__ out, int n) {
    const int wave = (blockIdx.x * blockDim.x + threadIdx.x) >> 6;
    if (wave >= n) return;
    const int lane = threadIdx.x & 63;

    const float2 a1 = ((const float2*)asum)[lane];
    const float2 a2 = ((const float2*)(asum + F_OUT))[lane];
    const float2 hs = ((const float2*)(h + (size_t)wave * F_OUT))[lane];

    // loop-invariant: lin_s = sum(hs * asum[:128])
    float ls = hs.x * a1.x + hs.y * a1.y;
    #pragma unroll
    for (int m = 32; m >= 1; m >>= 1) ls += __shfl_xor(ls, m, 64);

    const int start = partial[wave] + bscan[wave >> 8];
    const int deg = cnt[wave];

    float accx = 0.f, accy = 0.f, rs = 0.f;
    for (int j = 0; j < deg; ++j) {
        const int d = sdst[start + j];
        const float2 hd = ((const float2*)(h + (size_t)d * F_OUT))[lane];
        float pl = hd.x * a2.x + hd.y * a2.y;
        float pc = hs.x * hd.x + hs.y * hd.y;
        #pragma unroll
        for (int m = 32; m >= 1; m >>= 1) {
            pl += __shfl_xor(pl, m, 64);
            pc += __shfl_xor(pc, m, 64);
        }
        const float z = (ls + pl) / (1.0f + __expf(-pc));
        const float lr = (z >= 0.f) ? z : ALPHA * z;
        const float ee = __expf(-lr);
        accx += ee * hd.x;
        accy += ee * hd.y;
        rs += ee;
    }

    const float inv = 1.0f / (rs + 1e-8f);
    accx *= inv;
    accy *= inv;
    accx = (accx > 0.f) ? accx : (__expf(accx) - 1.f);
    accy = (accy > 0.f) ? accy : (__expf(accy) - 1.f);
    ((float2*)(out + (size_t)wave * F_OUT))[lane] = make_float2(accx, accy);
}

extern "C" void kernel_launch(void* const* d_in, const int* in_sizes, int n_in,
                              void* d_out, int out_size, void* d_ws, size_t ws_size,
                              hipStream_t stream) {
    const float* x = (const float*)d_in[0];
    const int* ei = (const int*)d_in[1];
    const float* W = (const float*)d_in[2];
    const float* a = (const float*)d_in[3];
    float* out = (float*)d_out;

    const int n = in_sizes[0] / F_IN;
    const int E = in_sizes[1] / 2;
    const int* src = ei;
    const int* dst = ei + E;
    const int nb = (n + 255) / 256;

    // workspace layout (16B-aligned regions)
    char* p = (char*)d_ws;
    float* h = (float*)p;           p += (size_t)n * F_OUT * 4;
    float* asum = (float*)p;        p += 256 * 4;
    int* cnt = (int*)p;             p += (size_t)n * 4;
    int* cur = (int*)p;             p += (size_t)n * 4;   // contiguous with cnt
    int* partial = (int*)p;         p += (size_t)n * 4;
    int* bscan = (int*)p;           p += ((nb + 3) & ~3) * 4;
    int* sdst = (int*)p;            p += (size_t)E * 4;

    // zero the counters (cnt + cur are contiguous)
    hipMemsetAsync(cnt, 0, (size_t)2 * n * sizeof(int), stream);

    asum_kernel<<<1, 256, 0, stream>>>(a, asum);
    gemm_kernel<<<(n + GR - 1) / GR, 256, 0, stream>>>(x, W, h, n);
    hist_kernel<<<(E + 255) / 256, 256, 0, stream>>>(src, cnt, E);
    scan1_kernel<<<nb, 256, 0, stream>>>(cnt, partial, bscan, n);
    scan2_kernel<<<1, 256, 0, stream>>>(bscan, nb);
    scatter_kernel<<<(E + 255) / 256, 256, 0, stream>>>(src, dst, partial, bscan, cur, sdst, E);
    agg_kernel<<<(n * 64 + 255) / 256, 256, 0, stream>>>(h, sdst, partial, bscan, cnt, asum, out, n);
}

// Round 3
// 292.760 us; speedup vs baseline: 2.9423x; 1.2167x over previous
//
#include <hip/hip_runtime.h>

#define F_IN 256
#define F_OUT 128
#define ALPHA 0.2f

// ---------------- asum: column sums of a [256,256] -> asum[256] ----------------
__global__ __launch_bounds__(256) void asum_kernel(const float* __restrict__ a,
                                                   float* __restrict__ asum) {
    int j = threadIdx.x;
    float s = 0.f;
    #pragma unroll 8
    for (int i = 0; i < 2 * F_OUT; ++i) s += a[i * (2 * F_OUT) + j];
    asum[j] = s;
}

// ---------------- GEMM v2: h[n,128] = x[n,256] @ W[256,128], fp32 ----------------
// 256 threads, tile 64 rows x 128 cols, GK=32. Thread: 8 rows x 4 cols.
// xT stored transposed so the row-fragment read is ds_read_b128.
#define TM 64
#define GK 32
__global__ __launch_bounds__(256) void gemm_kernel(const float* __restrict__ x,
                                                   const float* __restrict__ W,
                                                   float* __restrict__ h, int n) {
    __shared__ float xT[GK][TM + 4];   // transposed x tile, ~8.7 KB
    __shared__ float wsm[GK][F_OUT];   // 16 KB
    const int t = threadIdx.x;
    const int row0 = blockIdx.x * TM;
    const int tx = t & 31;   // cols tx*4..+4
    const int ty = t >> 5;   // rows ty*8..+8

    float acc[8][4] = {{0.f}};

    const int r = t & 63;         // row within tile for x load
    const int kseg = t >> 6;      // 0..3 -> k offset kseg*8
    int xrow = row0 + r;
    if (xrow >= n) xrow = n - 1;

    for (int kt = 0; kt < F_IN; kt += GK) {
        // load x: thread loads 8 consecutive k for one row, writes transposed
        {
            const float4* xg = (const float4*)(x + (size_t)xrow * F_IN + kt + kseg * 8);
            float4 v0 = xg[0];
            float4 v1 = xg[1];
            int k0 = kseg * 8;
            xT[k0 + 0][r] = v0.x; xT[k0 + 1][r] = v0.y;
            xT[k0 + 2][r] = v0.z; xT[k0 + 3][r] = v0.w;
            xT[k0 + 4][r] = v1.x; xT[k0 + 5][r] = v1.y;
            xT[k0 + 6][r] = v1.z; xT[k0 + 7][r] = v1.w;
        }
        // load W tile 32x128 = 1024 float4, 4 per thread, contiguous
        {
            const float4* Wg = (const float4*)(W + (size_t)kt * F_OUT);
            float4* Wl = (float4*)(&wsm[0][0]);
            #pragma unroll
            for (int it = 0; it < 4; ++it) Wl[t + it * 256] = Wg[t + it * 256];
        }
        __syncthreads();

        #pragma unroll 8
        for (int k = 0; k < GK; ++k) {
            float4 wv = *(float4*)(&wsm[k][tx * 4]);
            float4 xa = *(float4*)(&xT[k][ty * 8]);
            float4 xb = *(float4*)(&xT[k][ty * 8 + 4]);
            #pragma unroll
            for (int c = 0; c < 4; ++c) {
                float wc = (c == 0) ? wv.x : (c == 1) ? wv.y : (c == 2) ? wv.z : wv.w;
                acc[0][c] += xa.x * wc;
                acc[1][c] += xa.y * wc;
                acc[2][c] += xa.z * wc;
                acc[3][c] += xa.w * wc;
                acc[4][c] += xb.x * wc;
                acc[5][c] += xb.y * wc;
                acc[6][c] += xb.z * wc;
                acc[7][c] += xb.w * wc;
            }
        }
        __syncthreads();
    }

    #pragma unroll
    for (int rr = 0; rr < 8; ++rr) {
        int row = row0 + ty * 8 + rr;
        if (row < n) {
            float4 v = make_float4(acc[rr][0], acc[rr][1], acc[rr][2], acc[rr][3]);
            *(float4*)(&h[(size_t)row * F_OUT + tx * 4]) = v;
        }
    }
}

// ---------------- CSR build ----------------
__global__ __launch_bounds__(256) void hist_kernel(const int* __restrict__ src,
                                                   int* __restrict__ cnt, int E) {
    int i = blockIdx.x * blockDim.x + threadIdx.x;
    if (i < E) atomicAdd(&cnt[src[i]], 1);
}

__global__ __launch_bounds__(256) void scan1_kernel(const int* __restrict__ cnt,
                                                    int* __restrict__ partial,
                                                    int* __restrict__ bsums, int n) {
    const int i = blockIdx.x * 256 + threadIdx.x;
    const int lane = threadIdx.x & 63;
    const int wid = threadIdx.x >> 6;
    int v = (i < n) ? cnt[i] : 0;
    int x = v;
    #pragma unroll
    for (int m = 1; m < 64; m <<= 1) {
        int y = __shfl_up(x, m, 64);
        if (lane >= m) x += y;
    }
    __shared__ int wsum[4];
    if (lane == 63) wsum[wid] = x;
    __syncthreads();
    int ws0 = 0;
    for (int w = 0; w < wid; ++w) ws0 += wsum[w];
    int incl = x + ws0;
    if (i < n) partial[i] = incl - v;
    if (threadIdx.x == 255) bsums[blockIdx.x] = incl;
}

__global__ __launch_bounds__(256) void scan2_kernel(int* __restrict__ bsums, int nb) {
    const int t = threadIdx.x;
    const int lane = t & 63;
    const int wid = t >> 6;
    int v = (t < nb) ? bsums[t] : 0;
    int x = v;
    #pragma unroll
    for (int m = 1; m < 64; m <<= 1) {
        int y = __shfl_up(x, m, 64);
        if (lane >= m) x += y;
    }
    __shared__ int wsum[4];
    if (lane == 63) wsum[wid] = x;
    __syncthreads();
    int ws0 = 0;
    for (int w = 0; w < wid; ++w) ws0 += wsum[w];
    if (t < nb) bsums[t] = x + ws0 - v;
}

__global__ __launch_bounds__(256) void offs_kernel(const int* __restrict__ partial,
                                                   const int* __restrict__ bscan,
                                                   int* __restrict__ offs, int n) {
    int i = blockIdx.x * blockDim.x + threadIdx.x;
    if (i < n) offs[i] = partial[i] + bscan[i >> 8];
}

__global__ __launch_bounds__(256) void scatter_kernel(const int* __restrict__ src,
                                                      const int* __restrict__ dst,
                                                      const int* __restrict__ offs,
                                                      int* __restrict__ cur,
                                                      int* __restrict__ sdst, int E) {
    int i = blockIdx.x * blockDim.x + threadIdx.x;
    if (i >= E) return;
    int s = src[i];
    int pos = offs[s] + atomicAdd(&cur[s], 1);
    sdst[pos] = dst[i];
}

// ---------------- aggregation v2: wave per node, 4 edge-subgroups x 16 lanes ----------------
// lane = (g<<4)|q : subgroup g handles edge slot g, lane owns features q*8..q*8+8.
__global__ __launch_bounds__(256) void agg_kernel(const float* __restrict__ h,
                                                  const int* __restrict__ sdst,
                                                  const int* __restrict__ offs,
                                                  const int* __restrict__ cnt,
                                                  const float* __restrict__ asum,
                                                  float* __restrict__ out, int n) {
    const int wave = (blockIdx.x * blockDim.x + threadIdx.x) >> 6;
    if (wave >= n) return;
    const int lane = threadIdx.x & 63;
    const int q = lane & 15;
    const int g = lane >> 4;

    const float4* hrow = (const float4*)(h + (size_t)wave * F_OUT);
    const float4 hs0 = hrow[q * 2];
    const float4 hs1 = hrow[q * 2 + 1];
    const float4* a2p = (const float4*)(asum + F_OUT);
    const float4 a20 = a2p[q * 2];
    const float4 a21 = a2p[q * 2 + 1];

    // ls = hs . asum[:128]  (same value in every subgroup; reduce within 16 lanes)
    float ls;
    {
        const float4* a1p = (const float4*)asum;
        float4 a10 = a1p[q * 2];
        float4 a11 = a1p[q * 2 + 1];
        ls = hs0.x * a10.x + hs0.y * a10.y + hs0.z * a10.z + hs0.w * a10.w
           + hs1.x * a11.x + hs1.y * a11.y + hs1.z * a11.z + hs1.w * a11.w;
        #pragma unroll
        for (int m = 8; m >= 1; m >>= 1) ls += __shfl_xor(ls, m, 64);
    }

    const int start = offs[wave];
    const int deg = cnt[wave];

    float4 acc0 = make_float4(0.f, 0.f, 0.f, 0.f);
    float4 acc1 = make_float4(0.f, 0.f, 0.f, 0.f);
    float rs = 0.f;

    if (deg > 0) {
        int dcur = sdst[start + ((g < deg) ? g : 0)];
        for (int j0 = 0; j0 < deg; j0 += 4) {
            // prefetch next subgroup-edge index
            const bool has_next = (j0 + 4) < deg;
            int dnext = 0;
            if (has_next) {
                int jn = j0 + 4 + g;
                dnext = sdst[start + ((jn < deg) ? jn : 0)];
            }
            const float4* hdp = (const float4*)(h + (size_t)dcur * F_OUT);
            const float4 hd0 = hdp[q * 2];
            const float4 hd1 = hdp[q * 2 + 1];

            float pc = hs0.x * hd0.x + hs0.y * hd0.y + hs0.z * hd0.z + hs0.w * hd0.w
                     + hs1.x * hd1.x + hs1.y * hd1.y + hs1.z * hd1.z + hs1.w * hd1.w;
            float pl = a20.x * hd0.x + a20.y * hd0.y + a20.z * hd0.z + a20.w * hd0.w
                     + a21.x * hd1.x + a21.y * hd1.y + a21.z * hd1.z + a21.w * hd1.w;
            #pragma unroll
            for (int m = 8; m >= 1; m >>= 1) {
                pc += __shfl_xor(pc, m, 64);
                pl += __shfl_xor(pl, m, 64);
            }
            const float sig = 1.0f / (1.0f + __expf(-pc));
            const float z = (ls + pl) * sig;
            const float lr = (z >= 0.f) ? z : ALPHA * z;
            float ee = __expf(-lr);
            if (j0 + g >= deg) ee = 0.f;

            acc0.x += ee * hd0.x; acc0.y += ee * hd0.y;
            acc0.z += ee * hd0.z; acc0.w += ee * hd0.w;
            acc1.x += ee * hd1.x; acc1.y += ee * hd1.y;
            acc1.z += ee * hd1.z; acc1.w += ee * hd1.w;
            rs += ee;

            dcur = dnext;
        }
    }

    // combine across the 4 subgroups (xor 16, 32)
    #pragma unroll
    for (int m = 16; m <= 32; m <<= 1) {
        acc0.x += __shfl_xor(acc0.x, m, 64);
        acc0.y += __shfl_xor(acc0.y, m, 64);
        acc0.z += __shfl_xor(acc0.z, m, 64);
        acc0.w += __shfl_xor(acc0.w, m, 64);
        acc1.x += __shfl_xor(acc1.x, m, 64);
        acc1.y += __shfl_xor(acc1.y, m, 64);
        acc1.z += __shfl_xor(acc1.z, m, 64);
        acc1.w += __shfl_xor(acc1.w, m, 64);
        rs += __shfl_xor(rs, m, 64);
    }

    const float inv = 1.0f / (rs + 1e-8f);
    // lane (g,q) stores features q*8 + g*2, q*8 + g*2 + 1
    const float4 srcv = (g & 2) ? acc1 : acc0;
    float sx = ((g & 1) ? srcv.z : srcv.x) * inv;
    float sy = ((g & 1) ? srcv.w : srcv.y) * inv;
    sx = (sx > 0.f) ? sx : (__expf(sx) - 1.f);
    sy = (sy > 0.f) ? sy : (__expf(sy) - 1.f);
    *(float2*)(out + (size_t)wave * F_OUT + q * 8 + g * 2) = make_float2(sx, sy);
}

extern "C" void kernel_launch(void* const* d_in, const int* in_sizes, int n_in,
                              void* d_out, int out_size, void* d_ws, size_t ws_size,
                              hipStream_t stream) {
    const float* x = (const float*)d_in[0];
    const int* ei = (const int*)d_in[1];
    const float* W = (const float*)d_in[2];
    const float* a = (const float*)d_in[3];
    float* out = (float*)d_out;

    const int n = in_sizes[0] / F_IN;
    const int E = in_sizes[1] / 2;
    const int* src = ei;
    const int* dst = ei + E;
    const int nb = (n + 255) / 256;

    char* p = (char*)d_ws;
    float* h = (float*)p;       p += (size_t)n * F_OUT * 4;
    float* asum = (float*)p;    p += 256 * 4;
    int* cnt = (int*)p;         p += (size_t)n * 4;
    int* cur = (int*)p;         p += (size_t)n * 4;   // contiguous with cnt
    int* partial = (int*)p;     p += (size_t)n * 4;
    int* offs = (int*)p;        p += (size_t)n * 4;
    int* bscan = (int*)p;       p += ((nb + 3) & ~3) * 4;
    int* sdst = (int*)p;        p += (size_t)E * 4;

    hipMemsetAsync(cnt, 0, (size_t)2 * n * sizeof(int), stream);

    asum_kernel<<<1, 256, 0, stream>>>(a, asum);
    gemm_kernel<<<(n + TM - 1) / TM, 256, 0, stream>>>(x, W, h, n);
    hist_kernel<<<(E + 255) / 256, 256, 0, stream>>>(src, cnt, E);
    scan1_kernel<<<nb, 256, 0, stream>>>(cnt, partial, bscan, n);
    scan2_kernel<<<1, 256, 0, stream>>>(bscan, nb);
    offs_kernel<<<nb, 256, 0, stream>>>(partial, bscan, offs, n);
    scatter_kernel<<<(E + 255) / 256, 256, 0, stream>>>(src, dst, offs, cur, sdst, E);
    agg_kernel<<<(n * 64 + 255) / 256, 256, 0, stream>>>(h, sdst, offs, cnt, asum, out, n);
}